// Round 2
// baseline (1396.926 us; speedup 1.0000x reference)
//
#include <hip/hip_runtime.h>
#include <hip/hip_bf16.h>
#include <math.h>

#define D 256
#define NCAM 500
#define NPT 100000

// ============ sort-based aggregation (replaces 128M-fp32-atomic scatter) ====

__global__ void hist_kernel(const int* __restrict__ ci, const int* __restrict__ pi,
                            int* __restrict__ cam_cnt, int* __restrict__ pt_cnt, int E) {
    int i = blockIdx.x * 256 + threadIdx.x;
    if (i < E) {
        atomicAdd(&pt_cnt[pi[i]], 1);
        atomicAdd(&cam_cnt[ci[i]], 1);
    }
}

__global__ void scan_cam_kernel(const int* __restrict__ cnt,
                                int* __restrict__ start, int* __restrict__ cur) {
    __shared__ int s[512];
    int t = threadIdx.x;
    int v0 = (t < NCAM) ? cnt[t] : 0;
    s[t] = v0;
    __syncthreads();
    for (int off = 1; off < 512; off <<= 1) {
        int v = (t >= off) ? s[t - off] : 0;
        __syncthreads();
        s[t] += v;
        __syncthreads();
    }
    if (t < NCAM) {
        int ex = s[t] - v0;  // exclusive
        start[t] = ex;
        cur[t] = ex;
    }
}

__global__ void scan_pt_kernel(const int* __restrict__ cnt,
                               int* __restrict__ start, int* __restrict__ cur) {
    __shared__ int s[1024];
    const int CH = (NPT + 1023) / 1024;  // 98
    int t = threadIdx.x;
    int lo = t * CH;
    int hi = lo + CH; if (hi > NPT) hi = NPT;
    int sum = 0;
    for (int i = lo; i < hi; i++) sum += cnt[i];
    s[t] = sum;
    __syncthreads();
    for (int off = 1; off < 1024; off <<= 1) {
        int v = (t >= off) ? s[t - off] : 0;
        __syncthreads();
        s[t] += v;
        __syncthreads();
    }
    int run = s[t] - sum;  // exclusive prefix
    for (int i = lo; i < hi; i++) {
        start[i] = run;
        cur[i] = run;
        run += cnt[i];
    }
}

__global__ void fill_kernel(const int* __restrict__ ci, const int* __restrict__ pi,
                            int* __restrict__ cam_cur, int* __restrict__ pt_cur,
                            int* __restrict__ cam_list, int* __restrict__ pt_list, int E) {
    int i = blockIdx.x * 256 + threadIdx.x;
    if (i < E) {
        pt_list[atomicAdd(&pt_cur[pi[i]], 1)] = i;
        cam_list[atomicAdd(&cam_cur[ci[i]], 1)] = i;
    }
}

// one block per point: atomic-free segment sum
__global__ void pt_agg_kernel(const float* __restrict__ ef,
                              const int* __restrict__ pt_start, const int* __restrict__ pt_cnt,
                              const int* __restrict__ pt_list, float* __restrict__ pt_agg) {
    int p = blockIdx.x;
    int t = threadIdx.x;
    int s0 = pt_start[p], n = pt_cnt[p];
    float acc = 0.f;
    for (int j = 0; j < n; j++) {
        int e = pt_list[s0 + j];
        acc += ef[(size_t)e * D + t];
    }
    pt_agg[(size_t)p * D + t] = acc;
}

// 8 partial blocks per cam → cam_part[cam*8+part][256]
__global__ void cam_agg_kernel(const float* __restrict__ ef,
                               const int* __restrict__ cam_start, const int* __restrict__ cam_cnt,
                               const int* __restrict__ cam_list, float* __restrict__ cam_part) {
    int c = blockIdx.x >> 3;
    int part = blockIdx.x & 7;
    int t = threadIdx.x;
    int s0 = cam_start[c], n = cam_cnt[c];
    float acc = 0.f;
    for (int j = part; j < n; j += 8) {
        int e = cam_list[s0 + j];
        acc += ef[(size_t)e * D + t];
    }
    cam_part[(size_t)blockIdx.x * D + t] = acc;
}

// ============ weight folding (unchanged) ====================================
__global__ void combine_weights(const float* __restrict__ Wcam,
                                const float* __restrict__ Wpt,
                                const float* __restrict__ Wattn,
                                const float* __restrict__ Wfin,
                                float* __restrict__ CcamT,
                                float* __restrict__ Cpt,
                                float* __restrict__ vcam,
                                float* __restrict__ vpt) {
    int b = blockIdx.x;
    int i = threadIdx.x;
    if (b < 256) {
        int o = b;
        float acc = 0.f;
        for (int j = 0; j < 256; j++) acc += Wfin[o * 512 + j] * Wcam[j * 256 + i];
        CcamT[i * 256 + o] = acc;
    } else if (b < 512) {
        int o = b - 256;
        float acc = 0.f;
        for (int j = 0; j < 256; j++) acc += Wfin[o * 512 + 256 + j] * Wpt[j * 256 + i];
        Cpt[o * 256 + i] = acc;
    } else if (b == 512) {
        float acc = 0.f;
        for (int j = 0; j < 256; j++) acc += Wattn[j] * Wcam[j * 256 + i];
        vcam[i] = acc;
    } else {
        float acc = 0.f;
        for (int j = 0; j < 256; j++) acc += Wattn[256 + j] * Wpt[j * 256 + i];
        vpt[i] = acc;
    }
}

// ============ cam projection: reduces the 8 partials, then project ==========
__global__ void cam_proj(const float* __restrict__ cam_part,
                         const float* __restrict__ CcamT,
                         const float* __restrict__ vcam,
                         float* __restrict__ gcam,
                         float* __restrict__ acam) {
    __shared__ float row[256];
    __shared__ float red[256];
    int c = blockIdx.x;
    int t = threadIdx.x;
    float r = 0.f;
#pragma unroll
    for (int k = 0; k < 8; k++) r += cam_part[(size_t)(c * 8 + k) * 256 + t];
    row[t] = r;
    __syncthreads();
    float acc = 0.f;
    for (int i = 0; i < 256; i++) acc += row[i] * CcamT[i * 256 + t];
    gcam[(size_t)c * 256 + t] = acc;
    red[t] = r * vcam[t];
    __syncthreads();
    for (int s = 128; s > 0; s >>= 1) {
        if (t < s) red[t] += red[t + s];
        __syncthreads();
    }
    if (t == 0) acam[c] = red[0];
}

// ============ main GEMM: 128x128 tile, 8x8 per thread =======================
#define BM 128
#define BN 128
#define BK 32
__global__ __launch_bounds__(256) void gemm_pt(const float* __restrict__ A,
                                               const float* __restrict__ Bmat,
                                               float* __restrict__ Cout, int M) {
    __shared__ float As[BK][BM + 4];
    __shared__ float Bs[BK][BN + 4];
    int m0 = blockIdx.x * BM;
    int n0 = blockIdx.y * BN;
    int tid = threadIdx.x;
    int lrow = tid >> 1;           // 0..127
    int lcol = (tid & 1) * 16;     // 0 or 16
    int tm = (tid >> 4) << 3;      // 0..120
    int tn = (tid & 15) << 3;      // 0..120
    float acc[8][8] = {};
    int arow = m0 + lrow; if (arow > M - 1) arow = M - 1;  // clamp (stores guarded)
    for (int k0 = 0; k0 < 256; k0 += BK) {
        const float* ap = A + (size_t)arow * 256 + k0 + lcol;
        const float* bp = Bmat + (size_t)(n0 + lrow) * 256 + k0 + lcol;
        float4 a0 = *(const float4*)ap;
        float4 a1 = *(const float4*)(ap + 4);
        float4 a2 = *(const float4*)(ap + 8);
        float4 a3 = *(const float4*)(ap + 12);
        float4 b0 = *(const float4*)bp;
        float4 b1 = *(const float4*)(bp + 4);
        float4 b2 = *(const float4*)(bp + 8);
        float4 b3 = *(const float4*)(bp + 12);
        As[lcol + 0][lrow] = a0.x;  As[lcol + 1][lrow] = a0.y;
        As[lcol + 2][lrow] = a0.z;  As[lcol + 3][lrow] = a0.w;
        As[lcol + 4][lrow] = a1.x;  As[lcol + 5][lrow] = a1.y;
        As[lcol + 6][lrow] = a1.z;  As[lcol + 7][lrow] = a1.w;
        As[lcol + 8][lrow] = a2.x;  As[lcol + 9][lrow] = a2.y;
        As[lcol + 10][lrow] = a2.z; As[lcol + 11][lrow] = a2.w;
        As[lcol + 12][lrow] = a3.x; As[lcol + 13][lrow] = a3.y;
        As[lcol + 14][lrow] = a3.z; As[lcol + 15][lrow] = a3.w;
        Bs[lcol + 0][lrow] = b0.x;  Bs[lcol + 1][lrow] = b0.y;
        Bs[lcol + 2][lrow] = b0.z;  Bs[lcol + 3][lrow] = b0.w;
        Bs[lcol + 4][lrow] = b1.x;  Bs[lcol + 5][lrow] = b1.y;
        Bs[lcol + 6][lrow] = b1.z;  Bs[lcol + 7][lrow] = b1.w;
        Bs[lcol + 8][lrow] = b2.x;  Bs[lcol + 9][lrow] = b2.y;
        Bs[lcol + 10][lrow] = b2.z; Bs[lcol + 11][lrow] = b2.w;
        Bs[lcol + 12][lrow] = b3.x; Bs[lcol + 13][lrow] = b3.y;
        Bs[lcol + 14][lrow] = b3.z; Bs[lcol + 15][lrow] = b3.w;
        __syncthreads();
        for (int k = 0; k < BK; k++) {
            float a[8], b[8];
            *(float4*)&a[0] = *(const float4*)&As[k][tm];
            *(float4*)&a[4] = *(const float4*)&As[k][tm + 4];
            *(float4*)&b[0] = *(const float4*)&Bs[k][tn];
            *(float4*)&b[4] = *(const float4*)&Bs[k][tn + 4];
#pragma unroll
            for (int i = 0; i < 8; i++)
#pragma unroll
                for (int j = 0; j < 8; j++) acc[i][j] += a[i] * b[j];
        }
        __syncthreads();
    }
#pragma unroll
    for (int i = 0; i < 8; i++) {
        int m = m0 + tm + i;
        if (m < M) {
            *(float4*)&Cout[(size_t)m * 256 + n0 + tn] = make_float4(acc[i][0], acc[i][1], acc[i][2], acc[i][3]);
            *(float4*)&Cout[(size_t)m * 256 + n0 + tn + 4] = make_float4(acc[i][4], acc[i][5], acc[i][6], acc[i][7]);
        }
    }
}

// ============ a_pt[m] = A[m,:] . vpt ========================================
__global__ void apt_kernel(const float* __restrict__ A,
                           const float* __restrict__ vpt,
                           float* __restrict__ apt, int M) {
    __shared__ float vs[256];
    vs[threadIdx.x] = vpt[threadIdx.x];
    __syncthreads();
    int wave = threadIdx.x >> 6;
    int lane = threadIdx.x & 63;
    int row = blockIdx.x * 4 + wave;
    if (row >= M) return;
    const float* a = A + (size_t)row * 256;
    float acc = 0.f;
    for (int i = lane; i < 256; i += 64) acc += a[i] * vs[i];
    for (int off = 32; off > 0; off >>= 1) acc += __shfl_down(acc, off);
    if (lane == 0) apt[row] = acc;
}

// ============ softmax over edges ============================================
__device__ __forceinline__ unsigned float_key(float f) {
    unsigned b = __float_as_uint(f);
    return (b & 0x80000000u) ? ~b : (b | 0x80000000u);
}
__device__ __forceinline__ float key_float(unsigned k) {
    return __uint_as_float((k & 0x80000000u) ? (k & 0x7FFFFFFFu) : ~k);
}

__global__ void e_max_kernel(const int* __restrict__ ci, const int* __restrict__ pi,
                             const float* __restrict__ acam, const float* __restrict__ apt,
                             float* __restrict__ ebuf, unsigned* __restrict__ maxkey, int E) {
    int i = blockIdx.x * 256 + threadIdx.x;
    float e = -INFINITY;
    if (i < E) {
        e = acam[ci[i]] + apt[pi[i]];
        ebuf[i] = e;
    }
    __shared__ float red[256];
    int t = threadIdx.x;
    red[t] = e;
    __syncthreads();
    for (int s = 128; s > 0; s >>= 1) {
        if (t < s) red[t] = fmaxf(red[t], red[t + s]);
        __syncthreads();
    }
    if (t == 0) atomicMax(maxkey, float_key(red[0]));
}

__global__ void sumexp_kernel(float* __restrict__ ebuf,
                              const unsigned* __restrict__ maxkey,
                              float* __restrict__ sumexp, int E) {
    int i = blockIdx.x * 256 + threadIdx.x;
    float mx = key_float(*maxkey);
    float p = 0.f;
    if (i < E) {
        p = expf(ebuf[i] - mx);
        ebuf[i] = p;
    }
    __shared__ float red[256];
    int t = threadIdx.x;
    red[t] = p;
    __syncthreads();
    for (int s = 128; s > 0; s >>= 1) {
        if (t < s) red[t] += red[t + s];
        __syncthreads();
    }
    if (t == 0) atomicAdd(sumexp, red[0]);
}

// ============ output ========================================================
__global__ void out_kernel(const int* __restrict__ ci, const int* __restrict__ pi,
                           const float* __restrict__ gcam, const float* __restrict__ gpt,
                           const float* __restrict__ bfin, const float* __restrict__ ebuf,
                           const float* __restrict__ sumexp, float* __restrict__ out, int E) {
    int e = blockIdx.x;
    int t = threadIdx.x;
    float scale = ebuf[e] / (*sumexp);
    int c = ci[e];
    int p = pi[e];
    float v = (gcam[(size_t)c * 256 + t] + gpt[(size_t)p * 256 + t] + bfin[t]) * scale;
    out[(size_t)e * 256 + t] = fmaxf(v, 0.f);
}

extern "C" void kernel_launch(void* const* d_in, const int* in_sizes, int n_in,
                              void* d_out, int out_size, void* d_ws, size_t ws_size,
                              hipStream_t stream) {
    const float* ef    = (const float*)d_in[0];
    const int*   ci    = (const int*)d_in[1];
    const int*   pi    = (const int*)d_in[2];
    const float* Wcam  = (const float*)d_in[5];
    const float* Wpt   = (const float*)d_in[6];
    const float* Wattn = (const float*)d_in[7];
    const float* Wfin  = (const float*)d_in[8];
    const float* bfin  = (const float*)d_in[9];
    float* out = (float*)d_out;
    int E = in_sizes[0] / D;

    float* ws = (float*)d_ws;
    float* pt_agg   = ws;                               // 25,600,000
    float* CcamT    = pt_agg + (size_t)NPT * D;         // 65536
    float* Cpt      = CcamT + 65536;                    // 65536
    float* vcam     = Cpt + 65536;                      // 256
    float* vpt      = vcam + 256;                       // 256
    float* gcam     = vpt + 256;                        // 128000
    float* acam     = gcam + (size_t)NCAM * D;          // 512
    float* cam_part = acam + 512;                       // 500*8*256 = 1,024,000
    float* gpt      = cam_part + (size_t)NCAM * 8 * D;  // 25,600,000
    float* apt      = gpt + (size_t)NPT * D;            // 100000
    float* ebuf     = apt + NPT;                        // E
    unsigned* maxkey = (unsigned*)(ebuf + E);
    float* sumexp   = (float*)(maxkey + 1);

    // sort scratch aliases into gpt (only needed before gemm_pt writes gpt)
    int* sb        = (int*)gpt;
    int* pt_cnt    = sb;                 // 100000
    int* cam_cnt   = pt_cnt + NPT;       // 512
    int* pt_start  = cam_cnt + 512;      // 100000
    int* cam_start = pt_start + NPT;     // 512
    int* pt_cur    = cam_start + 512;    // 100000
    int* cam_cur   = pt_cur + NPT;       // 512
    int* pt_list   = cam_cur + 512;      // E
    int* cam_list  = pt_list + E;        // E

    hipMemsetAsync(pt_cnt, 0, (size_t)(NPT + 512) * sizeof(int), stream);
    hipMemsetAsync(maxkey, 0, 2 * sizeof(unsigned), stream);

    int eb = (E + 255) / 256;
    hist_kernel<<<eb, 256, 0, stream>>>(ci, pi, cam_cnt, pt_cnt, E);
    scan_cam_kernel<<<1, 512, 0, stream>>>(cam_cnt, cam_start, cam_cur);
    scan_pt_kernel<<<1, 1024, 0, stream>>>(pt_cnt, pt_start, pt_cur);
    fill_kernel<<<eb, 256, 0, stream>>>(ci, pi, cam_cur, pt_cur, cam_list, pt_list, E);
    pt_agg_kernel<<<NPT, 256, 0, stream>>>(ef, pt_start, pt_cnt, pt_list, pt_agg);
    cam_agg_kernel<<<NCAM * 8, 256, 0, stream>>>(ef, cam_start, cam_cnt, cam_list, cam_part);

    combine_weights<<<514, 256, 0, stream>>>(Wcam, Wpt, Wattn, Wfin, CcamT, Cpt, vcam, vpt);
    cam_proj<<<NCAM, 256, 0, stream>>>(cam_part, CcamT, vcam, gcam, acam);
    dim3 g4((NPT + BM - 1) / BM, 256 / BN);
    gemm_pt<<<g4, 256, 0, stream>>>(pt_agg, Cpt, gpt, NPT);
    apt_kernel<<<(NPT + 3) / 4, 256, 0, stream>>>(pt_agg, vpt, apt, NPT);
    e_max_kernel<<<eb, 256, 0, stream>>>(ci, pi, acam, apt, ebuf, maxkey, E);
    sumexp_kernel<<<eb, 256, 0, stream>>>(ebuf, maxkey, sumexp, E);
    out_kernel<<<E, 256, 0, stream>>>(ci, pi, gcam, gpt, bfin, ebuf, sumexp, out, E);
}